// Round 3
// baseline (3952.901 us; speedup 1.0000x reference)
//
#include <hip/hip_runtime.h>
#include <hip/hip_fp16.h>

// LSTM T=512 B=64 D=256 H=256, fp32 in/out.
//
// Phase 0: convert X to f16; build transposed f16 weights Wxt/Wht [4H][K].
// Phase 1: gx = X @ Wx + b via MFMA f16 GEMM (M=32768, K=256, N=1024) -> ws f16.
// Phase 2: recurrence, 1 CU per batch element, 512 threads (8 waves, 2/SIMD).
//          Thread owns 2 gate-columns. Wh resident: 96 half2-pairs/col in VGPRs
//          (192 VGPRs) + 32 pairs/col in LDS (128 KB). h broadcast via LDS.
//          __launch_bounds__(512,1): ensures 256-VGPR cap (round-2's (512,2)
//          was read as min-2-blocks/CU -> 128 cap -> weight spill).

#define T_STEPS 512
#define BATCH   64
#define HID     256
#define G4      1024                  // 4*HID
#define GM      (T_STEPS * BATCH)     // 32768

typedef _Float16 half2_t __attribute__((ext_vector_type(2)));
typedef _Float16 f16x8   __attribute__((ext_vector_type(8)));
typedef float    f32x4   __attribute__((ext_vector_type(4)));

// ws element offsets (f16 elements)
#define XH_OFF  0u          // [32768][256]  f16   8,388,608
#define WXT_OFF 8388608u    // [1024][256]   f16     262,144
#define WHT_OFF 8650752u    // [1024][256]   f16     262,144
#define GX_OFF  8912896u    // [32768][1024] f16  33,554,432  (total 84.9 MB)

__device__ __forceinline__ half2_t bc_f32(float f) {
    half2_t r; __builtin_memcpy(&r, &f, 4); return r;
}
__device__ __forceinline__ half2_t bc_u32(unsigned u) {
    half2_t r; __builtin_memcpy(&r, &u, 4); return r;
}
__device__ __forceinline__ float dot2acc(half2_t a, half2_t b, float c) {
#if __has_builtin(__builtin_amdgcn_fdot2)
    return __builtin_amdgcn_fdot2(a, b, c, false);
#else
    return c + (float)a.x * (float)b.x + (float)a.y * (float)b.y;
#endif
}
__device__ __forceinline__ float fast_sigmoid(float x) {
    return 1.0f / (1.0f + __expf(-x));
}
__device__ __forceinline__ float fast_tanh(float x) {
    return 2.0f / (1.0f + __expf(-2.0f * x)) - 1.0f;
}

// ---------------- Phase 0a: X f32 -> f16 ----------------
__global__ __launch_bounds__(256) void k_prep_x(const float* __restrict__ X,
                                                _Float16* __restrict__ Xh) {
    const int i = blockIdx.x * 256 + threadIdx.x;   // x4 floats
    float4 v = ((const float4*)X)[i];
    half2_t a; a.x = (_Float16)v.x; a.y = (_Float16)v.y;
    half2_t b; b.x = (_Float16)v.z; b.y = (_Float16)v.w;
    ((half2_t*)Xh)[2 * i]     = a;
    ((half2_t*)Xh)[2 * i + 1] = b;
}

// ---------------- Phase 0b: transpose weights to [4H][K] f16 ----------------
__global__ __launch_bounds__(256) void k_prep_w(
    const float* __restrict__ Wax, const float* __restrict__ Wix,
    const float* __restrict__ Wfx, const float* __restrict__ Wox,
    const float* __restrict__ Wah, const float* __restrict__ Wih,
    const float* __restrict__ Wfh, const float* __restrict__ Woh,
    _Float16* __restrict__ Wxt, _Float16* __restrict__ Wht)
{
    const int id  = blockIdx.x * 256 + threadIdx.x;   // [0, 524288)
    const int mat = id >> 18;                          // 0: Wx, 1: Wh
    const int idx = id & 262143;
    const int k   = idx >> 10;                         // [0,256)
    const int c   = idx & 1023;                        // gate column
    const int g   = c >> 8;
    const int j   = c & 255;
    const float* src;
    if (mat == 0) src = (g == 0) ? Wax : (g == 1) ? Wix : (g == 2) ? Wfx : Wox;
    else          src = (g == 0) ? Wah : (g == 1) ? Wih : (g == 2) ? Wfh : Woh;
    _Float16* dst = mat ? Wxt : Wht;
    dst = mat ? Wht : Wxt;
    dst[c * 256 + k] = (_Float16)src[k * 256 + j];
}

// ---------------- Phase 1: gx = Xh @ Wxt^T + b ----------------
// M=32768, N=1024, K=256. Block 256 thr = 4 waves; tile 128(M) x 64(N).
__global__ __launch_bounds__(256) void k_gemm(const _Float16* __restrict__ Xh,
                                              const _Float16* __restrict__ Wxt,
                                              const float* __restrict__ ba,
                                              const float* __restrict__ bi,
                                              const float* __restrict__ bf_,
                                              const float* __restrict__ bo,
                                              _Float16* __restrict__ gx)
{
    const int lane = threadIdx.x & 63, wave = threadIdx.x >> 6;
    const int rowbase = blockIdx.x * 128 + wave * 32;
    const int colbase = blockIdx.y * 64;
    const int r15 = lane & 15, kg = lane >> 4;   // kgroup 0..3 (8 k each)

    f32x4 acc[2][4] = {};
    const _Float16* ap0 = Xh  + (size_t)(rowbase + r15) * 256 + kg * 8;
    const _Float16* ap1 = ap0 + 16 * 256;
    const _Float16* bp  = Wxt + (size_t)(colbase + r15) * 256 + kg * 8;

#pragma unroll
    for (int ks = 0; ks < 8; ++ks) {
        f16x8 a0 = *(const f16x8*)(ap0 + ks * 32);
        f16x8 a1 = *(const f16x8*)(ap1 + ks * 32);
        f16x8 b0 = *(const f16x8*)(bp  + ks * 32);
        f16x8 b1 = *(const f16x8*)(bp  + 16 * 256 + ks * 32);
        f16x8 b2 = *(const f16x8*)(bp  + 32 * 256 + ks * 32);
        f16x8 b3 = *(const f16x8*)(bp  + 48 * 256 + ks * 32);
        acc[0][0] = __builtin_amdgcn_mfma_f32_16x16x32_f16(a0, b0, acc[0][0], 0, 0, 0);
        acc[0][1] = __builtin_amdgcn_mfma_f32_16x16x32_f16(a0, b1, acc[0][1], 0, 0, 0);
        acc[0][2] = __builtin_amdgcn_mfma_f32_16x16x32_f16(a0, b2, acc[0][2], 0, 0, 0);
        acc[0][3] = __builtin_amdgcn_mfma_f32_16x16x32_f16(a0, b3, acc[0][3], 0, 0, 0);
        acc[1][0] = __builtin_amdgcn_mfma_f32_16x16x32_f16(a1, b0, acc[1][0], 0, 0, 0);
        acc[1][1] = __builtin_amdgcn_mfma_f32_16x16x32_f16(a1, b1, acc[1][1], 0, 0, 0);
        acc[1][2] = __builtin_amdgcn_mfma_f32_16x16x32_f16(a1, b2, acc[1][2], 0, 0, 0);
        acc[1][3] = __builtin_amdgcn_mfma_f32_16x16x32_f16(a1, b3, acc[1][3], 0, 0, 0);
    }
    // bias per nt-tile column (col = colbase + nt*16 + r15)
    float bias_n[4];
#pragma unroll
    for (int nt = 0; nt < 4; ++nt) {
        int col = colbase + nt * 16 + r15;
        bias_n[nt] = (col < 256) ? ba[col]
                   : (col < 512) ? bi[col - 256]
                   : (col < 768) ? bf_[col - 512]
                                 : bo[col - 768];
    }
    // C/D layout (m89-verified): col = lane&15, row = (lane>>4)*4 + r
#pragma unroll
    for (int mt = 0; mt < 2; ++mt)
#pragma unroll
        for (int nt = 0; nt < 4; ++nt)
#pragma unroll
            for (int r = 0; r < 4; ++r) {
                int row = rowbase + mt * 16 + kg * 4 + r;
                int col = colbase + nt * 16 + r15;
                gx[(size_t)row * G4 + col] = (_Float16)(acc[mt][nt][r] + bias_n[nt]);
            }
}

// ---------------- Phase 2: recurrence ----------------
// 64 blocks x 512 threads. Thread owns gate-columns c0=tid, c1=tid+512.
// Wh column (K=256 f16 = 128 pairs): pairs 0..95 in VGPRs, 96..127 in LDS.
__global__ __launch_bounds__(512, 1) void k_recur(
    const _Float16* __restrict__ Wht, const _Float16* __restrict__ gx,
    float* __restrict__ out)
{
    const int b = blockIdx.x, tid = threadIdx.x;
    const int c0 = tid, c1 = tid + 512;

    __shared__ uint4 wl[16 * 512];                 // 128 KB weight tail
    __shared__ float act[1024];                    // 4 KB
    __shared__ __align__(16) _Float16 hbuf[256];   // 512 B

    // ---- load resident weights ----
    half2_t w0[96], w1[96];
    {
        const half2_t* s0 = (const half2_t*)(Wht + (size_t)c0 * 256);
        const half2_t* s1 = (const half2_t*)(Wht + (size_t)c1 * 256);
#pragma unroll
        for (int p = 0; p < 96; ++p) { w0[p] = s0[p]; w1[p] = s1[p]; }
        const uint4* q0 = (const uint4*)(Wht + (size_t)c0 * 256 + 192);
        const uint4* q1 = (const uint4*)(Wht + (size_t)c1 * 256 + 192);
#pragma unroll
        for (int i = 0; i < 8; ++i) {
            wl[i * 512 + tid]       = q0[i];       // col0 pairs 96+4i..+3
            wl[(8 + i) * 512 + tid] = q1[i];       // col1 pairs 96+4i..+3
        }
    }

    if (tid < 256) hbuf[tid] = (_Float16)0.0f;
    float s = 0.0f;
    _Float16 gc0 = gx[(size_t)b * G4 + c0];
    _Float16 gc1 = gx[(size_t)b * G4 + c1];
    __syncthreads();

    const float4* h4 = (const float4*)hbuf;

#pragma unroll 1
    for (int t = 0; t < T_STEPS; ++t) {
        // prefetch next-step gx early (covers L2/L3 latency under the dot)
        _Float16 gn0 = (_Float16)0.0f, gn1 = (_Float16)0.0f;
        if (t + 1 < T_STEPS) {
            const size_t m = (size_t)(t + 1) * BATCH + b;
            gn0 = gx[m * G4 + c0];
            gn1 = gx[m * G4 + c1];
        }

        float acc0 = (float)gc0;
        float acc1 = (float)gc1;

#pragma unroll
        for (int i2 = 0; i2 < 24; ++i2) {          // pairs 0..95 (registers)
            float4 hv = h4[i2];                     // uniform -> broadcast
            half2_t hp0 = bc_f32(hv.x), hp1 = bc_f32(hv.y);
            half2_t hp2 = bc_f32(hv.z), hp3 = bc_f32(hv.w);
            acc0 = dot2acc(hp0, w0[4 * i2 + 0], acc0);
            acc1 = dot2acc(hp0, w1[4 * i2 + 0], acc1);
            acc0 = dot2acc(hp1, w0[4 * i2 + 1], acc0);
            acc1 = dot2acc(hp1, w1[4 * i2 + 1], acc1);
            acc0 = dot2acc(hp2, w0[4 * i2 + 2], acc0);
            acc1 = dot2acc(hp2, w1[4 * i2 + 2], acc1);
            acc0 = dot2acc(hp3, w0[4 * i2 + 3], acc0);
            acc1 = dot2acc(hp3, w1[4 * i2 + 3], acc1);
        }
#pragma unroll
        for (int i2 = 0; i2 < 8; ++i2) {            // pairs 96..127 (LDS)
            float4 hv = h4[24 + i2];
            uint4 wa = wl[i2 * 512 + tid];          // lane-contiguous, no conflicts
            uint4 wb = wl[(8 + i2) * 512 + tid];
            acc0 = dot2acc(bc_f32(hv.x), bc_u32(wa.x), acc0);
            acc1 = dot2acc(bc_f32(hv.x), bc_u32(wb.x), acc1);
            acc0 = dot2acc(bc_f32(hv.y), bc_u32(wa.y), acc0);
            acc1 = dot2acc(bc_f32(hv.y), bc_u32(wb.y), acc1);
            acc0 = dot2acc(bc_f32(hv.z), bc_u32(wa.z), acc0);
            acc1 = dot2acc(bc_f32(hv.z), bc_u32(wb.z), acc1);
            acc0 = dot2acc(bc_f32(hv.w), bc_u32(wa.w), acc0);
            acc1 = dot2acc(bc_f32(hv.w), bc_u32(wb.w), acc1);
        }

        float av0 = (tid < 256) ? fast_tanh(acc0) : fast_sigmoid(acc0);
        float av1 = fast_sigmoid(acc1);
        act[c0] = av0;
        act[c1] = av1;
        __syncthreads();

        if (tid < 256) {
            float aa = act[tid], ii = act[tid + 256];
            float ff = act[tid + 512], oo = act[tid + 768];
            s = aa * ii + s * ff;
            float h = fast_tanh(s) * oo;
            out[((size_t)t * BATCH + b) * HID + tid] = h;
            hbuf[tid] = (_Float16)h;
        }
        __syncthreads();
        gc0 = gn0; gc1 = gn1;
    }
}

extern "C" void kernel_launch(void* const* d_in, const int* in_sizes, int n_in,
                              void* d_out, int out_size, void* d_ws, size_t ws_size,
                              hipStream_t stream) {
    const float* X   = (const float*)d_in[0];
    const float* Wax = (const float*)d_in[1];
    const float* Wix = (const float*)d_in[2];
    const float* Wfx = (const float*)d_in[3];
    const float* Wox = (const float*)d_in[4];
    const float* Wah = (const float*)d_in[5];
    const float* Wih = (const float*)d_in[6];
    const float* Wfh = (const float*)d_in[7];
    const float* Woh = (const float*)d_in[8];
    const float* ba  = (const float*)d_in[9];
    const float* bi  = (const float*)d_in[10];
    const float* bf  = (const float*)d_in[11];
    const float* bo  = (const float*)d_in[12];

    _Float16* ws  = (_Float16*)d_ws;
    _Float16* Xh  = ws + XH_OFF;
    _Float16* Wxt = ws + WXT_OFF;
    _Float16* Wht = ws + WHT_OFF;
    _Float16* gxp = ws + GX_OFF;

    k_prep_x<<<dim3(GM * 256 / 4 / 256), dim3(256), 0, stream>>>(X, Xh);
    k_prep_w<<<dim3(2048), dim3(256), 0, stream>>>(Wax, Wix, Wfx, Wox,
                                                   Wah, Wih, Wfh, Woh, Wxt, Wht);
    k_gemm<<<dim3(GM / 128, G4 / 64), dim3(256), 0, stream>>>(
        Xh, Wxt, ba, bi, bf, bo, gxp);
    k_recur<<<dim3(BATCH), dim3(512), 0, stream>>>(Wht, gxp, (float*)d_out);
}

// Round 4
// 3925.536 us; speedup vs baseline: 1.0070x; 1.0070x over previous
//
#include <hip/hip_runtime.h>
#include <hip/hip_fp16.h>

// LSTM T=512 B=64 D=256 H=256, fp32 in/out.
//
// Phase 0: convert X to f16; build transposed f16 weights Wxt/Wht [4H][K].
// Phase 1: gx = X @ Wx + b via MFMA f16 GEMM (M=32768, K=256, N=1024) -> ws f16.
// Phase 2: recurrence, 1 CU per batch element, 512 threads (8 waves, 2/SIMD).
//          Thread owns 2 gate-columns. Wh resident: pairs 0..95 per column in
//          NAMED f16x32 vector registers (12 x 16 VGPRs = 192; arrays were
//          getting scratch-demoted in R2/R3 -> VGPR_Count stuck at 128),
//          pairs 96..127 in LDS (128 KB). amdgpu_waves_per_eu(2,2) pins the
//          256-VGPR budget. h broadcast via LDS.

#define T_STEPS 512
#define BATCH   64
#define HID     256
#define G4      1024                  // 4*HID
#define GM      (T_STEPS * BATCH)     // 32768

typedef _Float16 half2_t __attribute__((ext_vector_type(2)));
typedef _Float16 f16x8   __attribute__((ext_vector_type(8)));
typedef _Float16 f16x32  __attribute__((ext_vector_type(32)));
typedef float    f32x4   __attribute__((ext_vector_type(4)));

// ws element offsets (f16 elements)
#define XH_OFF  0u          // [32768][256]  f16   8,388,608
#define WXT_OFF 8388608u    // [1024][256]   f16     262,144
#define WHT_OFF 8650752u    // [1024][256]   f16     262,144
#define GX_OFF  8912896u    // [32768][1024] f16  33,554,432  (total 84.9 MB)

__device__ __forceinline__ half2_t bc_f32(float f) {
    half2_t r; __builtin_memcpy(&r, &f, 4); return r;
}
__device__ __forceinline__ half2_t bc_u32(unsigned u) {
    half2_t r; __builtin_memcpy(&r, &u, 4); return r;
}
__device__ __forceinline__ float dot2acc(half2_t a, half2_t b, float c) {
#if __has_builtin(__builtin_amdgcn_fdot2)
    return __builtin_amdgcn_fdot2(a, b, c, false);
#else
    return c + (float)a.x * (float)b.x + (float)a.y * (float)b.y;
#endif
}
template <int I>
__device__ __forceinline__ half2_t pairof(f16x32 v) {
    return __builtin_shufflevector(v, v, 2 * I, 2 * I + 1);
}
__device__ __forceinline__ float fast_sigmoid(float x) {
    return 1.0f / (1.0f + __expf(-x));
}
__device__ __forceinline__ float fast_tanh(float x) {
    return 2.0f / (1.0f + __expf(-2.0f * x)) - 1.0f;
}

// ---------------- Phase 0a: X f32 -> f16 ----------------
__global__ __launch_bounds__(256) void k_prep_x(const float* __restrict__ X,
                                                _Float16* __restrict__ Xh) {
    const int i = blockIdx.x * 256 + threadIdx.x;   // x4 floats
    float4 v = ((const float4*)X)[i];
    half2_t a; a.x = (_Float16)v.x; a.y = (_Float16)v.y;
    half2_t b; b.x = (_Float16)v.z; b.y = (_Float16)v.w;
    ((half2_t*)Xh)[2 * i]     = a;
    ((half2_t*)Xh)[2 * i + 1] = b;
}

// ---------------- Phase 0b: transpose weights to [4H][K] f16 ----------------
__global__ __launch_bounds__(256) void k_prep_w(
    const float* __restrict__ Wax, const float* __restrict__ Wix,
    const float* __restrict__ Wfx, const float* __restrict__ Wox,
    const float* __restrict__ Wah, const float* __restrict__ Wih,
    const float* __restrict__ Wfh, const float* __restrict__ Woh,
    _Float16* __restrict__ Wxt, _Float16* __restrict__ Wht)
{
    const int id  = blockIdx.x * 256 + threadIdx.x;   // [0, 524288)
    const int mat = id >> 18;                          // 0: Wx, 1: Wh
    const int idx = id & 262143;
    const int k   = idx >> 10;                         // [0,256)
    const int c   = idx & 1023;                        // gate column
    const int g   = c >> 8;
    const int j   = c & 255;
    const float* src;
    if (mat == 0) src = (g == 0) ? Wax : (g == 1) ? Wix : (g == 2) ? Wfx : Wox;
    else          src = (g == 0) ? Wah : (g == 1) ? Wih : (g == 2) ? Wfh : Woh;
    _Float16* dst = mat ? Wht : Wxt;
    dst[c * 256 + k] = (_Float16)src[k * 256 + j];
}

// ---------------- Phase 1: gx = Xh @ Wxt^T + b ----------------
// M=32768, N=1024, K=256. Block 256 thr = 4 waves; tile 128(M) x 64(N).
__global__ __launch_bounds__(256) void k_gemm(const _Float16* __restrict__ Xh,
                                              const _Float16* __restrict__ Wxt,
                                              const float* __restrict__ ba,
                                              const float* __restrict__ bi,
                                              const float* __restrict__ bf_,
                                              const float* __restrict__ bo,
                                              _Float16* __restrict__ gx)
{
    const int lane = threadIdx.x & 63, wave = threadIdx.x >> 6;
    const int rowbase = blockIdx.x * 128 + wave * 32;
    const int colbase = blockIdx.y * 64;
    const int r15 = lane & 15, kg = lane >> 4;   // kgroup 0..3 (8 k each)

    f32x4 acc[2][4] = {};
    const _Float16* ap0 = Xh  + (size_t)(rowbase + r15) * 256 + kg * 8;
    const _Float16* ap1 = ap0 + 16 * 256;
    const _Float16* bp  = Wxt + (size_t)(colbase + r15) * 256 + kg * 8;

#pragma unroll
    for (int ks = 0; ks < 8; ++ks) {
        f16x8 a0 = *(const f16x8*)(ap0 + ks * 32);
        f16x8 a1 = *(const f16x8*)(ap1 + ks * 32);
        f16x8 b0 = *(const f16x8*)(bp  + ks * 32);
        f16x8 b1 = *(const f16x8*)(bp  + 16 * 256 + ks * 32);
        f16x8 b2 = *(const f16x8*)(bp  + 32 * 256 + ks * 32);
        f16x8 b3 = *(const f16x8*)(bp  + 48 * 256 + ks * 32);
        acc[0][0] = __builtin_amdgcn_mfma_f32_16x16x32_f16(a0, b0, acc[0][0], 0, 0, 0);
        acc[0][1] = __builtin_amdgcn_mfma_f32_16x16x32_f16(a0, b1, acc[0][1], 0, 0, 0);
        acc[0][2] = __builtin_amdgcn_mfma_f32_16x16x32_f16(a0, b2, acc[0][2], 0, 0, 0);
        acc[0][3] = __builtin_amdgcn_mfma_f32_16x16x32_f16(a0, b3, acc[0][3], 0, 0, 0);
        acc[1][0] = __builtin_amdgcn_mfma_f32_16x16x32_f16(a1, b0, acc[1][0], 0, 0, 0);
        acc[1][1] = __builtin_amdgcn_mfma_f32_16x16x32_f16(a1, b1, acc[1][1], 0, 0, 0);
        acc[1][2] = __builtin_amdgcn_mfma_f32_16x16x32_f16(a1, b2, acc[1][2], 0, 0, 0);
        acc[1][3] = __builtin_amdgcn_mfma_f32_16x16x32_f16(a1, b3, acc[1][3], 0, 0, 0);
    }
    // bias per nt-tile column (col = colbase + nt*16 + r15)
    float bias_n[4];
#pragma unroll
    for (int nt = 0; nt < 4; ++nt) {
        int col = colbase + nt * 16 + r15;
        bias_n[nt] = (col < 256) ? ba[col]
                   : (col < 512) ? bi[col - 256]
                   : (col < 768) ? bf_[col - 512]
                                 : bo[col - 768];
    }
    // C/D layout (m89-verified): col = lane&15, row = (lane>>4)*4 + r
#pragma unroll
    for (int mt = 0; mt < 2; ++mt)
#pragma unroll
        for (int nt = 0; nt < 4; ++nt)
#pragma unroll
            for (int r = 0; r < 4; ++r) {
                int row = rowbase + mt * 16 + kg * 4 + r;
                int col = colbase + nt * 16 + r15;
                gx[(size_t)row * G4 + col] = (_Float16)(acc[mt][nt][r] + bias_n[nt]);
            }
}

// ---------------- Phase 2: recurrence ----------------
// 64 blocks x 512 threads. Thread owns gate-columns c0=tid, c1=tid+512.
// Wh column (K=256 f16 = 128 pairs): pairs 0..95 in named f16x32 vector regs,
// pairs 96..127 in LDS.

#define DOTQ(WA, WB, P, HV)                      \
    acc0 = dot2acc(HV, pairof<P>(WA), acc0);     \
    acc1 = dot2acc(HV, pairof<P>(WB), acc1);

#define STEP16(WA, WB, q)                                                      \
  {                                                                            \
    float4 hv0 = h4[4 * (q)];     float4 hv1 = h4[4 * (q) + 1];                \
    float4 hv2 = h4[4 * (q) + 2]; float4 hv3 = h4[4 * (q) + 3];                \
    DOTQ(WA, WB, 0,  bc_f32(hv0.x)) DOTQ(WA, WB, 1,  bc_f32(hv0.y))            \
    DOTQ(WA, WB, 2,  bc_f32(hv0.z)) DOTQ(WA, WB, 3,  bc_f32(hv0.w))            \
    DOTQ(WA, WB, 4,  bc_f32(hv1.x)) DOTQ(WA, WB, 5,  bc_f32(hv1.y))            \
    DOTQ(WA, WB, 6,  bc_f32(hv1.z)) DOTQ(WA, WB, 7,  bc_f32(hv1.w))            \
    DOTQ(WA, WB, 8,  bc_f32(hv2.x)) DOTQ(WA, WB, 9,  bc_f32(hv2.y))            \
    DOTQ(WA, WB, 10, bc_f32(hv2.z)) DOTQ(WA, WB, 11, bc_f32(hv2.w))            \
    DOTQ(WA, WB, 12, bc_f32(hv3.x)) DOTQ(WA, WB, 13, bc_f32(hv3.y))            \
    DOTQ(WA, WB, 14, bc_f32(hv3.z)) DOTQ(WA, WB, 15, bc_f32(hv3.w))            \
  }

__global__ void __launch_bounds__(512)
__attribute__((amdgpu_waves_per_eu(2, 2)))
k_recur(const _Float16* __restrict__ Wht, const _Float16* __restrict__ gx,
        float* __restrict__ out)
{
    const int b = blockIdx.x, tid = threadIdx.x;
    const int c0 = tid, c1 = tid + 512;

    __shared__ uint4 wl[16 * 512];                 // 128 KB weight tail
    __shared__ float act[1024];                    // 4 KB
    __shared__ __align__(16) _Float16 hbuf[256];   // 512 B

    // ---- load resident weights (named SSA vectors -> must stay in VGPRs) ----
    const f16x32* s0 = (const f16x32*)(Wht + (size_t)c0 * 256);
    const f16x32* s1 = (const f16x32*)(Wht + (size_t)c1 * 256);
    f16x32 wa0 = s0[0], wa1 = s0[1], wa2 = s0[2];
    f16x32 wa3 = s0[3], wa4 = s0[4], wa5 = s0[5];
    f16x32 wb0 = s1[0], wb1 = s1[1], wb2 = s1[2];
    f16x32 wb3 = s1[3], wb4 = s1[4], wb5 = s1[5];
    {
        const uint4* q0 = (const uint4*)(Wht + (size_t)c0 * 256 + 192);
        const uint4* q1 = (const uint4*)(Wht + (size_t)c1 * 256 + 192);
#pragma unroll
        for (int i = 0; i < 8; ++i) {
            wl[i * 512 + tid]       = q0[i];       // col0 pairs 96+4i..+3
            wl[(8 + i) * 512 + tid] = q1[i];       // col1 pairs 96+4i..+3
        }
    }

    if (tid < 256) hbuf[tid] = (_Float16)0.0f;
    float s = 0.0f;
    _Float16 gc0 = gx[(size_t)b * G4 + c0];
    _Float16 gc1 = gx[(size_t)b * G4 + c1];
    __syncthreads();

    const float4* h4 = (const float4*)hbuf;

#pragma unroll 1
    for (int t = 0; t < T_STEPS; ++t) {
        // prefetch next-step gx early (covers L2/L3 latency under the dot)
        _Float16 gn0 = (_Float16)0.0f, gn1 = (_Float16)0.0f;
        if (t + 1 < T_STEPS) {
            const size_t m = (size_t)(t + 1) * BATCH + b;
            gn0 = gx[m * G4 + c0];
            gn1 = gx[m * G4 + c1];
        }

        float acc0 = (float)gc0;
        float acc1 = (float)gc1;

        // pairs 0..95 from register-resident vectors
        STEP16(wa0, wb0, 0)
        STEP16(wa1, wb1, 1)
        STEP16(wa2, wb2, 2)
        STEP16(wa3, wb3, 3)
        STEP16(wa4, wb4, 4)
        STEP16(wa5, wb5, 5)

#pragma unroll
        for (int i2 = 0; i2 < 8; ++i2) {            // pairs 96..127 (LDS)
            float4 hv = h4[24 + i2];
            uint4 wa = wl[i2 * 512 + tid];          // lane-contiguous, no conflicts
            uint4 wb = wl[(8 + i2) * 512 + tid];
            acc0 = dot2acc(bc_f32(hv.x), bc_u32(wa.x), acc0);
            acc1 = dot2acc(bc_f32(hv.x), bc_u32(wb.x), acc1);
            acc0 = dot2acc(bc_f32(hv.y), bc_u32(wa.y), acc0);
            acc1 = dot2acc(bc_f32(hv.y), bc_u32(wb.y), acc1);
            acc0 = dot2acc(bc_f32(hv.z), bc_u32(wa.z), acc0);
            acc1 = dot2acc(bc_f32(hv.z), bc_u32(wb.z), acc1);
            acc0 = dot2acc(bc_f32(hv.w), bc_u32(wa.w), acc0);
            acc1 = dot2acc(bc_f32(hv.w), bc_u32(wb.w), acc1);
        }

        float av0 = (tid < 256) ? fast_tanh(acc0) : fast_sigmoid(acc0);
        float av1 = fast_sigmoid(acc1);
        act[c0] = av0;
        act[c1] = av1;
        __syncthreads();

        if (tid < 256) {
            float aa = act[tid], ii = act[tid + 256];
            float ff = act[tid + 512], oo = act[tid + 768];
            s = aa * ii + s * ff;
            float h = fast_tanh(s) * oo;
            out[((size_t)t * BATCH + b) * HID + tid] = h;
            hbuf[tid] = (_Float16)h;
        }
        __syncthreads();
        gc0 = gn0; gc1 = gn1;
    }
}

extern "C" void kernel_launch(void* const* d_in, const int* in_sizes, int n_in,
                              void* d_out, int out_size, void* d_ws, size_t ws_size,
                              hipStream_t stream) {
    const float* X   = (const float*)d_in[0];
    const float* Wax = (const float*)d_in[1];
    const float* Wix = (const float*)d_in[2];
    const float* Wfx = (const float*)d_in[3];
    const float* Wox = (const float*)d_in[4];
    const float* Wah = (const float*)d_in[5];
    const float* Wih = (const float*)d_in[6];
    const float* Wfh = (const float*)d_in[7];
    const float* Woh = (const float*)d_in[8];
    const float* ba  = (const float*)d_in[9];
    const float* bi  = (const float*)d_in[10];
    const float* bf  = (const float*)d_in[11];
    const float* bo  = (const float*)d_in[12];

    _Float16* ws  = (_Float16*)d_ws;
    _Float16* Xh  = ws + XH_OFF;
    _Float16* Wxt = ws + WXT_OFF;
    _Float16* Wht = ws + WHT_OFF;
    _Float16* gxp = ws + GX_OFF;

    k_prep_x<<<dim3(GM * 256 / 4 / 256), dim3(256), 0, stream>>>(X, Xh);
    k_prep_w<<<dim3(2048), dim3(256), 0, stream>>>(Wax, Wix, Wfx, Wox,
                                                   Wah, Wih, Wfh, Woh, Wxt, Wht);
    k_gemm<<<dim3(GM / 128, G4 / 64), dim3(256), 0, stream>>>(
        Xh, Wxt, ba, bi, bf, bo, gxp);
    k_recur<<<dim3(BATCH), dim3(512), 0, stream>>>(Wht, gxp, (float*)d_out);
}

// Round 6
// 1826.001 us; speedup vs baseline: 2.1648x; 2.1498x over previous
//
#include <hip/hip_runtime.h>
#include <hip/hip_fp16.h>

// LSTM T=512 B=64 D=256 H=256, fp32 in/out.
//
// Phase 0: convert X to f16; build transposed f16 weights Wxt/Wht [4H][K].
// Phase 1: gx = X @ Wx + b via MFMA f16 GEMM (M=32768, K=256, N=1024) -> ws f16.
// Phase 2: recurrence, 1 CU per batch element, 256 threads (4 waves, 1/SIMD ->
//          unified 512-reg budget/wave: 256 arch + 256 AGPR; CDNA spills
//          VGPR->AGPR via accvgpr, not scratch). Thread owns 4 consecutive
//          gate-columns (same gate -> wave-uniform activation). Per col:
//          pairs 0..95 in regs (4x96=384 regs), pairs 96..127 in LDS (128 KB).
//
// (Round 5 bench died with an infra UnresponsiveContainer error before any
//  dispatch was profiled; identical resubmission to collect the measurement.)

#define T_STEPS 512
#define BATCH   64
#define HID     256
#define G4      1024                  // 4*HID
#define GM      (T_STEPS * BATCH)     // 32768

typedef _Float16 half2_t __attribute__((ext_vector_type(2)));
typedef _Float16 f16x8   __attribute__((ext_vector_type(8)));
typedef _Float16 f16x32  __attribute__((ext_vector_type(32)));
typedef float    f32x4   __attribute__((ext_vector_type(4)));

// ws element offsets (f16 elements)
#define XH_OFF  0u          // [32768][256]  f16   8,388,608
#define WXT_OFF 8388608u    // [1024][256]   f16     262,144
#define WHT_OFF 8650752u    // [1024][256]   f16     262,144
#define GX_OFF  8912896u    // [32768][1024] f16  33,554,432  (total 84.9 MB)

__device__ __forceinline__ half2_t bc_f32(float f) {
    half2_t r; __builtin_memcpy(&r, &f, 4); return r;
}
__device__ __forceinline__ half2_t bc_u32(unsigned u) {
    half2_t r; __builtin_memcpy(&r, &u, 4); return r;
}
__device__ __forceinline__ float dot2acc(half2_t a, half2_t b, float c) {
#if __has_builtin(__builtin_amdgcn_fdot2)
    return __builtin_amdgcn_fdot2(a, b, c, false);
#else
    return c + (float)a.x * (float)b.x + (float)a.y * (float)b.y;
#endif
}
template <int I>
__device__ __forceinline__ half2_t pairof(f16x32 v) {
    return __builtin_shufflevector(v, v, 2 * I, 2 * I + 1);
}
__device__ __forceinline__ float fast_sigmoid(float x) {
    return 1.0f / (1.0f + __expf(-x));
}
__device__ __forceinline__ float fast_tanh(float x) {
    return 2.0f / (1.0f + __expf(-2.0f * x)) - 1.0f;
}

// ---------------- Phase 0a: X f32 -> f16 ----------------
__global__ __launch_bounds__(256) void k_prep_x(const float* __restrict__ X,
                                                _Float16* __restrict__ Xh) {
    const int i = blockIdx.x * 256 + threadIdx.x;   // x4 floats
    float4 v = ((const float4*)X)[i];
    half2_t a; a.x = (_Float16)v.x; a.y = (_Float16)v.y;
    half2_t b; b.x = (_Float16)v.z; b.y = (_Float16)v.w;
    ((half2_t*)Xh)[2 * i]     = a;
    ((half2_t*)Xh)[2 * i + 1] = b;
}

// ---------------- Phase 0b: transpose weights to [4H][K] f16 ----------------
__global__ __launch_bounds__(256) void k_prep_w(
    const float* __restrict__ Wax, const float* __restrict__ Wix,
    const float* __restrict__ Wfx, const float* __restrict__ Wox,
    const float* __restrict__ Wah, const float* __restrict__ Wih,
    const float* __restrict__ Wfh, const float* __restrict__ Woh,
    _Float16* __restrict__ Wxt, _Float16* __restrict__ Wht)
{
    const int id  = blockIdx.x * 256 + threadIdx.x;   // [0, 524288)
    const int mat = id >> 18;                          // 0: Wx, 1: Wh
    const int idx = id & 262143;
    const int k   = idx >> 10;                         // [0,256)
    const int c   = idx & 1023;                        // gate column
    const int g   = c >> 8;
    const int j   = c & 255;
    const float* src;
    if (mat == 0) src = (g == 0) ? Wax : (g == 1) ? Wix : (g == 2) ? Wfx : Wox;
    else          src = (g == 0) ? Wah : (g == 1) ? Wih : (g == 2) ? Wfh : Woh;
    _Float16* dst = mat ? Wht : Wxt;
    dst[c * 256 + k] = (_Float16)src[k * 256 + j];
}

// ---------------- Phase 1: gx = Xh @ Wxt^T + b ----------------
// M=32768, N=1024, K=256. Block 256 thr = 4 waves; tile 128(M) x 64(N).
__global__ __launch_bounds__(256) void k_gemm(const _Float16* __restrict__ Xh,
                                              const _Float16* __restrict__ Wxt,
                                              const float* __restrict__ ba,
                                              const float* __restrict__ bi,
                                              const float* __restrict__ bf_,
                                              const float* __restrict__ bo,
                                              _Float16* __restrict__ gx)
{
    const int lane = threadIdx.x & 63, wave = threadIdx.x >> 6;
    const int rowbase = blockIdx.x * 128 + wave * 32;
    const int colbase = blockIdx.y * 64;
    const int r15 = lane & 15, kg = lane >> 4;   // kgroup 0..3 (8 k each)

    f32x4 acc[2][4] = {};
    const _Float16* ap0 = Xh  + (size_t)(rowbase + r15) * 256 + kg * 8;
    const _Float16* ap1 = ap0 + 16 * 256;
    const _Float16* bp  = Wxt + (size_t)(colbase + r15) * 256 + kg * 8;

#pragma unroll
    for (int ks = 0; ks < 8; ++ks) {
        f16x8 a0 = *(const f16x8*)(ap0 + ks * 32);
        f16x8 a1 = *(const f16x8*)(ap1 + ks * 32);
        f16x8 b0 = *(const f16x8*)(bp  + ks * 32);
        f16x8 b1 = *(const f16x8*)(bp  + 16 * 256 + ks * 32);
        f16x8 b2 = *(const f16x8*)(bp  + 32 * 256 + ks * 32);
        f16x8 b3 = *(const f16x8*)(bp  + 48 * 256 + ks * 32);
        acc[0][0] = __builtin_amdgcn_mfma_f32_16x16x32_f16(a0, b0, acc[0][0], 0, 0, 0);
        acc[0][1] = __builtin_amdgcn_mfma_f32_16x16x32_f16(a0, b1, acc[0][1], 0, 0, 0);
        acc[0][2] = __builtin_amdgcn_mfma_f32_16x16x32_f16(a0, b2, acc[0][2], 0, 0, 0);
        acc[0][3] = __builtin_amdgcn_mfma_f32_16x16x32_f16(a0, b3, acc[0][3], 0, 0, 0);
        acc[1][0] = __builtin_amdgcn_mfma_f32_16x16x32_f16(a1, b0, acc[1][0], 0, 0, 0);
        acc[1][1] = __builtin_amdgcn_mfma_f32_16x16x32_f16(a1, b1, acc[1][1], 0, 0, 0);
        acc[1][2] = __builtin_amdgcn_mfma_f32_16x16x32_f16(a1, b2, acc[1][2], 0, 0, 0);
        acc[1][3] = __builtin_amdgcn_mfma_f32_16x16x32_f16(a1, b3, acc[1][3], 0, 0, 0);
    }
    // bias per nt-tile column (col = colbase + nt*16 + r15)
    float bias_n[4];
#pragma unroll
    for (int nt = 0; nt < 4; ++nt) {
        int col = colbase + nt * 16 + r15;
        bias_n[nt] = (col < 256) ? ba[col]
                   : (col < 512) ? bi[col - 256]
                   : (col < 768) ? bf_[col - 512]
                                 : bo[col - 768];
    }
    // C/D layout (m89-verified): col = lane&15, row = (lane>>4)*4 + r
#pragma unroll
    for (int mt = 0; mt < 2; ++mt)
#pragma unroll
        for (int nt = 0; nt < 4; ++nt)
#pragma unroll
            for (int r = 0; r < 4; ++r) {
                int row = rowbase + mt * 16 + kg * 4 + r;
                int col = colbase + nt * 16 + r15;
                gx[(size_t)row * G4 + col] = (_Float16)(acc[mt][nt][r] + bias_n[nt]);
            }
}

// ---------------- Phase 2: recurrence ----------------
// 64 blocks x 256 threads (4 waves, 1/SIMD). Thread owns cols 4*tid..4*tid+3
// (all same gate: gate = tid>>6, wave-uniform). Per col: pairs 0..95 in regs
// (6 x f16x32 per col), pairs 96..127 in LDS.

#define DOTP(K, P, HV)                            \
    acc0 = dot2acc(HV, pairof<P>(wA##K), acc0);   \
    acc1 = dot2acc(HV, pairof<P>(wB##K), acc1);   \
    acc2 = dot2acc(HV, pairof<P>(wC##K), acc2);   \
    acc3 = dot2acc(HV, pairof<P>(wD##K), acc3);

#define CHUNK16(K)                                                             \
  {                                                                            \
    float4 hv0 = h4[4 * (K)];     float4 hv1 = h4[4 * (K) + 1];                \
    float4 hv2 = h4[4 * (K) + 2]; float4 hv3 = h4[4 * (K) + 3];                \
    DOTP(K, 0,  bc_f32(hv0.x)) DOTP(K, 1,  bc_f32(hv0.y))                      \
    DOTP(K, 2,  bc_f32(hv0.z)) DOTP(K, 3,  bc_f32(hv0.w))                      \
    DOTP(K, 4,  bc_f32(hv1.x)) DOTP(K, 5,  bc_f32(hv1.y))                      \
    DOTP(K, 6,  bc_f32(hv1.z)) DOTP(K, 7,  bc_f32(hv1.w))                      \
    DOTP(K, 8,  bc_f32(hv2.x)) DOTP(K, 9,  bc_f32(hv2.y))                      \
    DOTP(K, 10, bc_f32(hv2.z)) DOTP(K, 11, bc_f32(hv2.w))                      \
    DOTP(K, 12, bc_f32(hv3.x)) DOTP(K, 13, bc_f32(hv3.y))                      \
    DOTP(K, 14, bc_f32(hv3.z)) DOTP(K, 15, bc_f32(hv3.w))                      \
  }

__global__ void __launch_bounds__(256, 1)
__attribute__((amdgpu_waves_per_eu(1, 1)))
k_recur(const _Float16* __restrict__ Wht, const _Float16* __restrict__ gx,
        float* __restrict__ out)
{
    const int b = blockIdx.x, tid = threadIdx.x;
    const int c0 = 4 * tid;            // cols c0..c0+3, gate = tid>>6
    const int gate = tid >> 6;

    __shared__ uint4 wl[32 * 256];                 // 128 KB weight tail
    __shared__ float act[1024];                    // 4 KB
    __shared__ __align__(16) _Float16 hbuf[256];   // 512 B

    // ---- resident weights: 6 f16x32 chunks (96 pairs) per column ----
    const f16x32* sA = (const f16x32*)(Wht + (size_t)(c0 + 0) * 256);
    const f16x32* sB = (const f16x32*)(Wht + (size_t)(c0 + 1) * 256);
    const f16x32* sC = (const f16x32*)(Wht + (size_t)(c0 + 2) * 256);
    const f16x32* sD = (const f16x32*)(Wht + (size_t)(c0 + 3) * 256);
    f16x32 wA0 = sA[0], wA1 = sA[1], wA2 = sA[2];
    f16x32 wA3 = sA[3], wA4 = sA[4], wA5 = sA[5];
    f16x32 wB0 = sB[0], wB1 = sB[1], wB2 = sB[2];
    f16x32 wB3 = sB[3], wB4 = sB[4], wB5 = sB[5];
    f16x32 wC0 = sC[0], wC1 = sC[1], wC2 = sC[2];
    f16x32 wC3 = sC[3], wC4 = sC[4], wC5 = sC[5];
    f16x32 wD0 = sD[0], wD1 = sD[1], wD2 = sD[2];
    f16x32 wD3 = sD[3], wD4 = sD[4], wD5 = sD[5];
    // ---- tail pairs 96..127 -> LDS ----
#pragma unroll
    for (int q = 0; q < 4; ++q) {
        const uint4* src = (const uint4*)(Wht + (size_t)(c0 + q) * 256 + 192);
#pragma unroll
        for (int i = 0; i < 8; ++i)
            wl[(q * 8 + i) * 256 + tid] = src[i];
    }

    hbuf[tid] = (_Float16)0.0f;
    float s = 0.0f;
    uint2 gcu = *(const uint2*)(gx + (size_t)b * G4 + c0);   // step 0
    __syncthreads();

    const float4* h4 = (const float4*)hbuf;

#pragma unroll 1
    for (int t = 0; t < T_STEPS; ++t) {
        // prefetch next-step gx (one 8B load; covers HBM latency under dots)
        uint2 gnx; gnx.x = 0u; gnx.y = 0u;
        if (t + 1 < T_STEPS) {
            gnx = *(const uint2*)(gx + ((size_t)(t + 1) * BATCH + b) * G4 + c0);
        }

        half2_t g01 = bc_u32(gcu.x), g23 = bc_u32(gcu.y);
        float acc0 = (float)g01.x, acc1 = (float)g01.y;
        float acc2 = (float)g23.x, acc3 = (float)g23.y;

        // pairs 0..95 from register-resident vectors
        CHUNK16(0) CHUNK16(1) CHUNK16(2)
        CHUNK16(3) CHUNK16(4) CHUNK16(5)

        // pairs 96..127 from LDS
#pragma unroll
        for (int i = 0; i < 8; ++i) {
            float4 hv = h4[24 + i];
            half2_t hx = bc_f32(hv.x), hy = bc_f32(hv.y);
            half2_t hz = bc_f32(hv.z), hw = bc_f32(hv.w);
            uint4 t0 = wl[(0 * 8 + i) * 256 + tid];
            uint4 t1 = wl[(1 * 8 + i) * 256 + tid];
            uint4 t2 = wl[(2 * 8 + i) * 256 + tid];
            uint4 t3 = wl[(3 * 8 + i) * 256 + tid];
            acc0 = dot2acc(hx, bc_u32(t0.x), acc0);
            acc0 = dot2acc(hy, bc_u32(t0.y), acc0);
            acc0 = dot2acc(hz, bc_u32(t0.z), acc0);
            acc0 = dot2acc(hw, bc_u32(t0.w), acc0);
            acc1 = dot2acc(hx, bc_u32(t1.x), acc1);
            acc1 = dot2acc(hy, bc_u32(t1.y), acc1);
            acc1 = dot2acc(hz, bc_u32(t1.z), acc1);
            acc1 = dot2acc(hw, bc_u32(t1.w), acc1);
            acc2 = dot2acc(hx, bc_u32(t2.x), acc2);
            acc2 = dot2acc(hy, bc_u32(t2.y), acc2);
            acc2 = dot2acc(hz, bc_u32(t2.z), acc2);
            acc2 = dot2acc(hw, bc_u32(t2.w), acc2);
            acc3 = dot2acc(hx, bc_u32(t3.x), acc3);
            acc3 = dot2acc(hy, bc_u32(t3.y), acc3);
            acc3 = dot2acc(hz, bc_u32(t3.z), acc3);
            acc3 = dot2acc(hw, bc_u32(t3.w), acc3);
        }

        // activation (gate uniform per wave: gate 0 = tanh, else sigmoid)
        float4 av;
        if (gate == 0) {
            av.x = fast_tanh(acc0); av.y = fast_tanh(acc1);
            av.z = fast_tanh(acc2); av.w = fast_tanh(acc3);
        } else {
            av.x = fast_sigmoid(acc0); av.y = fast_sigmoid(acc1);
            av.z = fast_sigmoid(acc2); av.w = fast_sigmoid(acc3);
        }
        ((float4*)act)[tid] = av;
        __syncthreads();

        // h/s update: thread tid owns hidden unit j = tid
        {
            float aa = act[tid], ii = act[tid + 256];
            float ff = act[tid + 512], oo = act[tid + 768];
            s = aa * ii + s * ff;
            float h = fast_tanh(s) * oo;
            out[((size_t)t * BATCH + b) * HID + tid] = h;
            hbuf[tid] = (_Float16)h;
        }
        __syncthreads();
        gcu = gnx;
    }
}

extern "C" void kernel_launch(void* const* d_in, const int* in_sizes, int n_in,
                              void* d_out, int out_size, void* d_ws, size_t ws_size,
                              hipStream_t stream) {
    const float* X   = (const float*)d_in[0];
    const float* Wax = (const float*)d_in[1];
    const float* Wix = (const float*)d_in[2];
    const float* Wfx = (const float*)d_in[3];
    const float* Wox = (const float*)d_in[4];
    const float* Wah = (const float*)d_in[5];
    const float* Wih = (const float*)d_in[6];
    const float* Wfh = (const float*)d_in[7];
    const float* Woh = (const float*)d_in[8];
    const float* ba  = (const float*)d_in[9];
    const float* bi  = (const float*)d_in[10];
    const float* bf  = (const float*)d_in[11];
    const float* bo  = (const float*)d_in[12];

    _Float16* ws  = (_Float16*)d_ws;
    _Float16* Xh  = ws + XH_OFF;
    _Float16* Wxt = ws + WXT_OFF;
    _Float16* Wht = ws + WHT_OFF;
    _Float16* gxp = ws + GX_OFF;

    k_prep_x<<<dim3(GM * 256 / 4 / 256), dim3(256), 0, stream>>>(X, Xh);
    k_prep_w<<<dim3(2048), dim3(256), 0, stream>>>(Wax, Wix, Wfx, Wox,
                                                   Wah, Wih, Wfh, Woh, Wxt, Wht);
    k_gemm<<<dim3(GM / 128, G4 / 64), dim3(256), 0, stream>>>(
        Xh, Wxt, ba, bi, bf, bo, gxp);
    k_recur<<<dim3(BATCH), dim3(256), 0, stream>>>(Wht, gxp, (float*)d_out);
}

// Round 7
// 1668.359 us; speedup vs baseline: 2.3693x; 1.0945x over previous
//
#include <hip/hip_runtime.h>
#include <hip/hip_fp16.h>

// LSTM T=512 B=64 D=256 H=256, fp32 in/out.
//
// Phase 0: convert X to f16; build transposed f16 weights Wxt/Wht [4H][K].
// Phase 1: gx = X @ Wx + b via MFMA f16 GEMM (M=32768, K=256, N=1024) -> ws f16.
// Phase 2: recurrence, 1 CU per batch element, 256 threads (4 waves, 1/SIMD,
//          512-reg unified budget). GATE-MAJOR: thread j owns unit j's 4 gate
//          columns (j, 256+j, 512+j, 768+j) -> s/h update is thread-local,
//          ONE barrier/step, double-buffered h. Dots via v_pk_fma_f16
//          (R6 counters showed the fdot2 fallback cost 6 VALU ops/pair).
//          Per col: pairs 0..95 in named f16x32 regs (384 regs total),
//          pairs 96..127 in LDS (128 KB).

#define T_STEPS 512
#define BATCH   64
#define HID     256
#define G4      1024                  // 4*HID
#define GM      (T_STEPS * BATCH)     // 32768

typedef _Float16 half2_t __attribute__((ext_vector_type(2)));
typedef _Float16 f16x8   __attribute__((ext_vector_type(8)));
typedef _Float16 f16x32  __attribute__((ext_vector_type(32)));
typedef float    f32x4   __attribute__((ext_vector_type(4)));

// ws element offsets (f16 elements)
#define XH_OFF  0u          // [32768][256]  f16   8,388,608
#define WXT_OFF 8388608u    // [1024][256]   f16     262,144
#define WHT_OFF 8650752u    // [1024][256]   f16     262,144
#define GX_OFF  8912896u    // [32768][1024] f16  33,554,432  (total 84.9 MB)

__device__ __forceinline__ half2_t bc_u32(unsigned u) {
    half2_t r; __builtin_memcpy(&r, &u, 4); return r;
}
template <int I>
__device__ __forceinline__ half2_t pairof(f16x32 v) {
    return __builtin_shufflevector(v, v, 2 * I, 2 * I + 1);
}
__device__ __forceinline__ float fast_sigmoid(float x) {
    return 1.0f / (1.0f + __expf(-x));
}
__device__ __forceinline__ float fast_tanh(float x) {
    return 2.0f / (1.0f + __expf(-2.0f * x)) - 1.0f;
}

// ---------------- Phase 0a: X f32 -> f16 ----------------
__global__ __launch_bounds__(256) void k_prep_x(const float* __restrict__ X,
                                                _Float16* __restrict__ Xh) {
    const int i = blockIdx.x * 256 + threadIdx.x;   // x4 floats
    float4 v = ((const float4*)X)[i];
    half2_t a; a.x = (_Float16)v.x; a.y = (_Float16)v.y;
    half2_t b; b.x = (_Float16)v.z; b.y = (_Float16)v.w;
    ((half2_t*)Xh)[2 * i]     = a;
    ((half2_t*)Xh)[2 * i + 1] = b;
}

// ---------------- Phase 0b: transpose weights to [4H][K] f16 ----------------
__global__ __launch_bounds__(256) void k_prep_w(
    const float* __restrict__ Wax, const float* __restrict__ Wix,
    const float* __restrict__ Wfx, const float* __restrict__ Wox,
    const float* __restrict__ Wah, const float* __restrict__ Wih,
    const float* __restrict__ Wfh, const float* __restrict__ Woh,
    _Float16* __restrict__ Wxt, _Float16* __restrict__ Wht)
{
    const int id  = blockIdx.x * 256 + threadIdx.x;   // [0, 524288)
    const int mat = id >> 18;                          // 0: Wx, 1: Wh
    const int idx = id & 262143;
    const int k   = idx >> 10;                         // [0,256)
    const int c   = idx & 1023;                        // gate column
    const int g   = c >> 8;
    const int j   = c & 255;
    const float* src;
    if (mat == 0) src = (g == 0) ? Wax : (g == 1) ? Wix : (g == 2) ? Wfx : Wox;
    else          src = (g == 0) ? Wah : (g == 1) ? Wih : (g == 2) ? Wfh : Woh;
    _Float16* dst = mat ? Wht : Wxt;
    dst[c * 256 + k] = (_Float16)src[k * 256 + j];
}

// ---------------- Phase 1: gx = Xh @ Wxt^T + b ----------------
// M=32768, N=1024, K=256. Block 256 thr = 4 waves; tile 128(M) x 64(N).
__global__ __launch_bounds__(256) void k_gemm(const _Float16* __restrict__ Xh,
                                              const _Float16* __restrict__ Wxt,
                                              const float* __restrict__ ba,
                                              const float* __restrict__ bi,
                                              const float* __restrict__ bf_,
                                              const float* __restrict__ bo,
                                              _Float16* __restrict__ gx)
{
    const int lane = threadIdx.x & 63, wave = threadIdx.x >> 6;
    const int rowbase = blockIdx.x * 128 + wave * 32;
    const int colbase = blockIdx.y * 64;
    const int r15 = lane & 15, kg = lane >> 4;   // kgroup 0..3 (8 k each)

    f32x4 acc[2][4] = {};
    const _Float16* ap0 = Xh  + (size_t)(rowbase + r15) * 256 + kg * 8;
    const _Float16* ap1 = ap0 + 16 * 256;
    const _Float16* bp  = Wxt + (size_t)(colbase + r15) * 256 + kg * 8;

#pragma unroll
    for (int ks = 0; ks < 8; ++ks) {
        f16x8 a0 = *(const f16x8*)(ap0 + ks * 32);
        f16x8 a1 = *(const f16x8*)(ap1 + ks * 32);
        f16x8 b0 = *(const f16x8*)(bp  + ks * 32);
        f16x8 b1 = *(const f16x8*)(bp  + 16 * 256 + ks * 32);
        f16x8 b2 = *(const f16x8*)(bp  + 32 * 256 + ks * 32);
        f16x8 b3 = *(const f16x8*)(bp  + 48 * 256 + ks * 32);
        acc[0][0] = __builtin_amdgcn_mfma_f32_16x16x32_f16(a0, b0, acc[0][0], 0, 0, 0);
        acc[0][1] = __builtin_amdgcn_mfma_f32_16x16x32_f16(a0, b1, acc[0][1], 0, 0, 0);
        acc[0][2] = __builtin_amdgcn_mfma_f32_16x16x32_f16(a0, b2, acc[0][2], 0, 0, 0);
        acc[0][3] = __builtin_amdgcn_mfma_f32_16x16x32_f16(a0, b3, acc[0][3], 0, 0, 0);
        acc[1][0] = __builtin_amdgcn_mfma_f32_16x16x32_f16(a1, b0, acc[1][0], 0, 0, 0);
        acc[1][1] = __builtin_amdgcn_mfma_f32_16x16x32_f16(a1, b1, acc[1][1], 0, 0, 0);
        acc[1][2] = __builtin_amdgcn_mfma_f32_16x16x32_f16(a1, b2, acc[1][2], 0, 0, 0);
        acc[1][3] = __builtin_amdgcn_mfma_f32_16x16x32_f16(a1, b3, acc[1][3], 0, 0, 0);
    }
    // bias per nt-tile column (col = colbase + nt*16 + r15)
    float bias_n[4];
#pragma unroll
    for (int nt = 0; nt < 4; ++nt) {
        int col = colbase + nt * 16 + r15;
        bias_n[nt] = (col < 256) ? ba[col]
                   : (col < 512) ? bi[col - 256]
                   : (col < 768) ? bf_[col - 512]
                                 : bo[col - 768];
    }
    // C/D layout (m89-verified): col = lane&15, row = (lane>>4)*4 + r
#pragma unroll
    for (int mt = 0; mt < 2; ++mt)
#pragma unroll
        for (int nt = 0; nt < 4; ++nt)
#pragma unroll
            for (int r = 0; r < 4; ++r) {
                int row = rowbase + mt * 16 + kg * 4 + r;
                int col = colbase + nt * 16 + r15;
                gx[(size_t)row * G4 + col] = (_Float16)(acc[mt][nt][r] + bias_n[nt]);
            }
}

// ---------------- Phase 2: recurrence ----------------
// 64 blocks x 256 threads (4 waves, 1/SIMD). Thread j owns gate columns
// {j, 256+j, 512+j, 768+j} (a,i,f,o of hidden unit j). Per col: pairs 0..95
// in named f16x32 regs, pairs 96..127 in LDS. f16 pk_fma accumulation with
// 4 sub-accumulators per gate. One barrier/step; h double-buffered.

// Q(P, S, HP): pair P of each gate's chunk, sub-acc S, h-pair HP
#define Q(P, S, HP)                              \
    { half2_t hp_ = (HP);                        \
      aA##S = pairof<P>(WA_) * hp_ + aA##S;      \
      aB##S = pairof<P>(WB_) * hp_ + aB##S;      \
      aC##S = pairof<P>(WC_) * hp_ + aC##S;      \
      aD##S = pairof<P>(WD_) * hp_ + aD##S; }

#define CHUNK(K)                                                               \
  {                                                                            \
    const f16x32 WA_ = wA##K, WB_ = wB##K, WC_ = wC##K, WD_ = wD##K;           \
    uint4 u0 = hsrc[4 * (K) + 0], u1 = hsrc[4 * (K) + 1];                      \
    uint4 u2 = hsrc[4 * (K) + 2], u3 = hsrc[4 * (K) + 3];                      \
    Q(0, 0, bc_u32(u0.x)) Q(1, 1, bc_u32(u0.y))                                \
    Q(2, 2, bc_u32(u0.z)) Q(3, 3, bc_u32(u0.w))                                \
    Q(4, 0, bc_u32(u1.x)) Q(5, 1, bc_u32(u1.y))                                \
    Q(6, 2, bc_u32(u1.z)) Q(7, 3, bc_u32(u1.w))                                \
    Q(8, 0, bc_u32(u2.x)) Q(9, 1, bc_u32(u2.y))                                \
    Q(10, 2, bc_u32(u2.z)) Q(11, 3, bc_u32(u2.w))                              \
    Q(12, 0, bc_u32(u3.x)) Q(13, 1, bc_u32(u3.y))                              \
    Q(14, 2, bc_u32(u3.z)) Q(15, 3, bc_u32(u3.w))                              \
  }

__global__ void __launch_bounds__(256, 1)
__attribute__((amdgpu_waves_per_eu(1, 1)))
k_recur(const _Float16* __restrict__ Wht, const _Float16* __restrict__ gx,
        float* __restrict__ out)
{
    const int b = blockIdx.x, j = threadIdx.x;

    __shared__ uint4 wl[32 * 256];                          // 128 KB weight tail
    __shared__ __align__(16) _Float16 hbuf[2][256];         // double-buffered h

    // ---- resident weights: cols A=j (a), B=256+j (i), C=512+j (f), D=768+j (o)
    const f16x32* sA = (const f16x32*)(Wht + (size_t)(j)       * 256);
    const f16x32* sB = (const f16x32*)(Wht + (size_t)(256 + j) * 256);
    const f16x32* sC = (const f16x32*)(Wht + (size_t)(512 + j) * 256);
    const f16x32* sD = (const f16x32*)(Wht + (size_t)(768 + j) * 256);
    f16x32 wA0 = sA[0], wA1 = sA[1], wA2 = sA[2];
    f16x32 wA3 = sA[3], wA4 = sA[4], wA5 = sA[5];
    f16x32 wB0 = sB[0], wB1 = sB[1], wB2 = sB[2];
    f16x32 wB3 = sB[3], wB4 = sB[4], wB5 = sB[5];
    f16x32 wC0 = sC[0], wC1 = sC[1], wC2 = sC[2];
    f16x32 wC3 = sC[3], wC4 = sC[4], wC5 = sC[5];
    f16x32 wD0 = sD[0], wD1 = sD[1], wD2 = sD[2];
    f16x32 wD3 = sD[3], wD4 = sD[4], wD5 = sD[5];
    // ---- tail pairs 96..127 -> LDS (lane-contiguous uint4 rows) ----
#pragma unroll
    for (int g = 0; g < 4; ++g) {
        const uint4* src = (const uint4*)(Wht + (size_t)(g * 256 + j) * 256 + 192);
#pragma unroll
        for (int i = 0; i < 8; ++i)
            wl[(g * 8 + i) * 256 + j] = src[i];
    }

    hbuf[0][j] = (_Float16)0.0f;
    float s = 0.0f;
    // step-0 gate inputs
    _Float16 gc0 = gx[(size_t)b * G4 + j];
    _Float16 gc1 = gx[(size_t)b * G4 + 256 + j];
    _Float16 gc2 = gx[(size_t)b * G4 + 512 + j];
    _Float16 gc3 = gx[(size_t)b * G4 + 768 + j];
    __syncthreads();

#pragma unroll 1
    for (int t = 0; t < T_STEPS; ++t) {
        // prefetch next-step gx (4 x 2B coalesced loads)
        _Float16 gn0 = (_Float16)0.0f, gn1 = (_Float16)0.0f;
        _Float16 gn2 = (_Float16)0.0f, gn3 = (_Float16)0.0f;
        if (t + 1 < T_STEPS) {
            const size_t m = ((size_t)(t + 1) * BATCH + b) * G4;
            gn0 = gx[m + j];       gn1 = gx[m + 256 + j];
            gn2 = gx[m + 512 + j]; gn3 = gx[m + 768 + j];
        }

        const uint4* hsrc = (const uint4*)hbuf[t & 1];

        half2_t aA0 = {}, aA1 = {}, aA2 = {}, aA3 = {};
        half2_t aB0 = {}, aB1 = {}, aB2 = {}, aB3 = {};
        half2_t aC0 = {}, aC1 = {}, aC2 = {}, aC3 = {};
        half2_t aD0 = {}, aD1 = {}, aD2 = {}, aD3 = {};

        // pairs 0..95 from register-resident vectors (h broadcast from LDS)
        CHUNK(0) CHUNK(1) CHUNK(2) CHUNK(3) CHUNK(4) CHUNK(5)

        // pairs 96..127: weights from LDS
#pragma unroll
        for (int i = 0; i < 8; ++i) {
            uint4 hu = hsrc[24 + i];
            half2_t q0 = bc_u32(hu.x), q1 = bc_u32(hu.y);
            half2_t q2 = bc_u32(hu.z), q3 = bc_u32(hu.w);
            uint4 tA = wl[(0 + i) * 256 + j];
            uint4 tB = wl[(8 + i) * 256 + j];
            uint4 tC = wl[(16 + i) * 256 + j];
            uint4 tD = wl[(24 + i) * 256 + j];
            aA0 = bc_u32(tA.x) * q0 + aA0;  aA1 = bc_u32(tA.y) * q1 + aA1;
            aA2 = bc_u32(tA.z) * q2 + aA2;  aA3 = bc_u32(tA.w) * q3 + aA3;
            aB0 = bc_u32(tB.x) * q0 + aB0;  aB1 = bc_u32(tB.y) * q1 + aB1;
            aB2 = bc_u32(tB.z) * q2 + aB2;  aB3 = bc_u32(tB.w) * q3 + aB3;
            aC0 = bc_u32(tC.x) * q0 + aC0;  aC1 = bc_u32(tC.y) * q1 + aC1;
            aC2 = bc_u32(tC.z) * q2 + aC2;  aC3 = bc_u32(tC.w) * q3 + aC3;
            aD0 = bc_u32(tD.x) * q0 + aD0;  aD1 = bc_u32(tD.y) * q1 + aD1;
            aD2 = bc_u32(tD.z) * q2 + aD2;  aD3 = bc_u32(tD.w) * q3 + aD3;
        }

        // horizontal reduce per gate (f16 pk adds, then f32)
        half2_t rA = (aA0 + aA1) + (aA2 + aA3);
        half2_t rB = (aB0 + aB1) + (aB2 + aB3);
        half2_t rC = (aC0 + aC1) + (aC2 + aC3);
        half2_t rD = (aD0 + aD1) + (aD2 + aD3);
        float gA = (float)rA.x + (float)rA.y + (float)gc0;
        float gB = (float)rB.x + (float)rB.y + (float)gc1;
        float gC = (float)rC.x + (float)rC.y + (float)gc2;
        float gD = (float)rD.x + (float)rD.y + (float)gc3;

        float aa = fast_tanh(gA);
        float ii = fast_sigmoid(gB);
        float ff = fast_sigmoid(gC);
        float oo = fast_sigmoid(gD);
        s = aa * ii + s * ff;
        float h = fast_tanh(s) * oo;
        out[((size_t)t * BATCH + b) * HID + j] = h;
        hbuf[(t + 1) & 1][j] = (_Float16)h;
        __syncthreads();

        gc0 = gn0; gc1 = gn1; gc2 = gn2; gc3 = gn3;
    }
}

extern "C" void kernel_launch(void* const* d_in, const int* in_sizes, int n_in,
                              void* d_out, int out_size, void* d_ws, size_t ws_size,
                              hipStream_t stream) {
    const float* X   = (const float*)d_in[0];
    const float* Wax = (const float*)d_in[1];
    const float* Wix = (const float*)d_in[2];
    const float* Wfx = (const float*)d_in[3];
    const float* Wox = (const float*)d_in[4];
    const float* Wah = (const float*)d_in[5];
    const float* Wih = (const float*)d_in[6];
    const float* Wfh = (const float*)d_in[7];
    const float* Woh = (const float*)d_in[8];
    const float* ba  = (const float*)d_in[9];
    const float* bi  = (const float*)d_in[10];
    const float* bf  = (const float*)d_in[11];
    const float* bo  = (const float*)d_in[12];

    _Float16* ws  = (_Float16*)d_ws;
    _Float16* Xh  = ws + XH_OFF;
    _Float16* Wxt = ws + WXT_OFF;
    _Float16* Wht = ws + WHT_OFF;
    _Float16* gxp = ws + GX_OFF;

    k_prep_x<<<dim3(GM * 256 / 4 / 256), dim3(256), 0, stream>>>(X, Xh);
    k_prep_w<<<dim3(2048), dim3(256), 0, stream>>>(Wax, Wix, Wfx, Wox,
                                                   Wah, Wih, Wfh, Woh, Wxt, Wht);
    k_gemm<<<dim3(GM / 128, G4 / 64), dim3(256), 0, stream>>>(
        Xh, Wxt, ba, bi, bf, bo, gxp);
    k_recur<<<dim3(BATCH), dim3(256), 0, stream>>>(Wht, gxp, (float*)d_out);
}

// Round 9
// 1050.155 us; speedup vs baseline: 3.7641x; 1.5887x over previous
//
#include <hip/hip_runtime.h>
#include <hip/hip_fp16.h>

// LSTM T=512 B=64 D=256 H=256, fp32 in/out.
//
// Phase 0: convert X to f16; build transposed f16 weights Wxt/Wht [4H][K].
// Phase 1: gx = X @ Wx + b via MFMA f16 GEMM (M=32768, K=256, N=1024) -> ws f16.
// Phase 2: recurrence, 1 CU per batch, 512 threads (8 waves, 2/SIMD -> TLP).
//          SPLIT-K: thread (j=tid>>1, half=tid&1) computes all 4 gates of unit
//          j over h-pairs [half*64, half*64+64); cross-half combine via
//          __shfl_xor(.,1). gc (gx input) added AFTER the combine (R8 bug:
//          added per-half -> counted twice -> absmax 0.22). Per gate: 48 pairs
//          in named u32x16 regs (192 VGPRs), 16 pairs in LDS (128 KB).
//          __hfma2 -> v_pk_fma_f16.

#define T_STEPS 512
#define BATCH   64
#define HID     256
#define G4      1024                  // 4*HID
#define GM      (T_STEPS * BATCH)     // 32768

typedef _Float16 half2_t __attribute__((ext_vector_type(2)));
typedef _Float16 f16x8   __attribute__((ext_vector_type(8)));
typedef unsigned u32x16  __attribute__((ext_vector_type(16)));   // 16 f16-pairs
typedef float    f32x4   __attribute__((ext_vector_type(4)));

// ws element offsets (f16 elements)
#define XH_OFF  0u          // [32768][256]  f16   8,388,608
#define WXT_OFF 8388608u    // [1024][256]   f16     262,144
#define WHT_OFF 8650752u    // [1024][256]   f16     262,144
#define GX_OFF  8912896u    // [32768][1024] f16  33,554,432  (total 84.9 MB)

__device__ __forceinline__ __half2 H2(unsigned u) {
    __half2 r; __builtin_memcpy(&r, &u, 4); return r;
}
__device__ __forceinline__ float fast_sigmoid(float x) {
    return 1.0f / (1.0f + __expf(-x));
}
__device__ __forceinline__ float fast_tanh(float x) {
    return 2.0f / (1.0f + __expf(-2.0f * x)) - 1.0f;
}

// ---------------- Phase 0a: X f32 -> f16 ----------------
__global__ __launch_bounds__(256) void k_prep_x(const float* __restrict__ X,
                                                _Float16* __restrict__ Xh) {
    const int i = blockIdx.x * 256 + threadIdx.x;   // x4 floats
    float4 v = ((const float4*)X)[i];
    half2_t a; a.x = (_Float16)v.x; a.y = (_Float16)v.y;
    half2_t b; b.x = (_Float16)v.z; b.y = (_Float16)v.w;
    ((half2_t*)Xh)[2 * i]     = a;
    ((half2_t*)Xh)[2 * i + 1] = b;
}

// ---------------- Phase 0b: transpose weights to [4H][K] f16 ----------------
__global__ __launch_bounds__(256) void k_prep_w(
    const float* __restrict__ Wax, const float* __restrict__ Wix,
    const float* __restrict__ Wfx, const float* __restrict__ Wox,
    const float* __restrict__ Wah, const float* __restrict__ Wih,
    const float* __restrict__ Wfh, const float* __restrict__ Woh,
    _Float16* __restrict__ Wxt, _Float16* __restrict__ Wht)
{
    const int id  = blockIdx.x * 256 + threadIdx.x;   // [0, 524288)
    const int mat = id >> 18;                          // 0: Wx, 1: Wh
    const int idx = id & 262143;
    const int k   = idx >> 10;                         // [0,256)
    const int c   = idx & 1023;                        // gate column
    const int g   = c >> 8;
    const int j   = c & 255;
    const float* src;
    if (mat == 0) src = (g == 0) ? Wax : (g == 1) ? Wix : (g == 2) ? Wfx : Wox;
    else          src = (g == 0) ? Wah : (g == 1) ? Wih : (g == 2) ? Wfh : Woh;
    _Float16* dst = mat ? Wht : Wxt;
    dst[c * 256 + k] = (_Float16)src[k * 256 + j];
}

// ---------------- Phase 1: gx = Xh @ Wxt^T + b ----------------
// M=32768, N=1024, K=256. Block 256 thr = 4 waves; tile 128(M) x 64(N).
__global__ __launch_bounds__(256) void k_gemm(const _Float16* __restrict__ Xh,
                                              const _Float16* __restrict__ Wxt,
                                              const float* __restrict__ ba,
                                              const float* __restrict__ bi,
                                              const float* __restrict__ bf_,
                                              const float* __restrict__ bo,
                                              _Float16* __restrict__ gx)
{
    const int lane = threadIdx.x & 63, wave = threadIdx.x >> 6;
    const int rowbase = blockIdx.x * 128 + wave * 32;
    const int colbase = blockIdx.y * 64;
    const int r15 = lane & 15, kg = lane >> 4;   // kgroup 0..3 (8 k each)

    f32x4 acc[2][4] = {};
    const _Float16* ap0 = Xh  + (size_t)(rowbase + r15) * 256 + kg * 8;
    const _Float16* ap1 = ap0 + 16 * 256;
    const _Float16* bp  = Wxt + (size_t)(colbase + r15) * 256 + kg * 8;

#pragma unroll
    for (int ks = 0; ks < 8; ++ks) {
        f16x8 a0 = *(const f16x8*)(ap0 + ks * 32);
        f16x8 a1 = *(const f16x8*)(ap1 + ks * 32);
        f16x8 b0 = *(const f16x8*)(bp  + ks * 32);
        f16x8 b1 = *(const f16x8*)(bp  + 16 * 256 + ks * 32);
        f16x8 b2 = *(const f16x8*)(bp  + 32 * 256 + ks * 32);
        f16x8 b3 = *(const f16x8*)(bp  + 48 * 256 + ks * 32);
        acc[0][0] = __builtin_amdgcn_mfma_f32_16x16x32_f16(a0, b0, acc[0][0], 0, 0, 0);
        acc[0][1] = __builtin_amdgcn_mfma_f32_16x16x32_f16(a0, b1, acc[0][1], 0, 0, 0);
        acc[0][2] = __builtin_amdgcn_mfma_f32_16x16x32_f16(a0, b2, acc[0][2], 0, 0, 0);
        acc[0][3] = __builtin_amdgcn_mfma_f32_16x16x32_f16(a0, b3, acc[0][3], 0, 0, 0);
        acc[1][0] = __builtin_amdgcn_mfma_f32_16x16x32_f16(a1, b0, acc[1][0], 0, 0, 0);
        acc[1][1] = __builtin_amdgcn_mfma_f32_16x16x32_f16(a1, b1, acc[1][1], 0, 0, 0);
        acc[1][2] = __builtin_amdgcn_mfma_f32_16x16x32_f16(a1, b2, acc[1][2], 0, 0, 0);
        acc[1][3] = __builtin_amdgcn_mfma_f32_16x16x32_f16(a1, b3, acc[1][3], 0, 0, 0);
    }
    // bias per nt-tile column (col = colbase + nt*16 + r15)
    float bias_n[4];
#pragma unroll
    for (int nt = 0; nt < 4; ++nt) {
        int col = colbase + nt * 16 + r15;
        bias_n[nt] = (col < 256) ? ba[col]
                   : (col < 512) ? bi[col - 256]
                   : (col < 768) ? bf_[col - 512]
                                 : bo[col - 768];
    }
    // C/D layout (m89-verified): col = lane&15, row = (lane>>4)*4 + r
#pragma unroll
    for (int mt = 0; mt < 2; ++mt)
#pragma unroll
        for (int nt = 0; nt < 4; ++nt)
#pragma unroll
            for (int r = 0; r < 4; ++r) {
                int row = rowbase + mt * 16 + kg * 4 + r;
                int col = colbase + nt * 16 + r15;
                gx[(size_t)row * G4 + col] = (_Float16)(acc[mt][nt][r] + bias_n[nt]);
            }
}

// ---------------- Phase 2: recurrence (split-K, 2 waves/SIMD) ----------------

// 16 pairs from a u32x16 weight chunk W against h-quads h0..h3
#define G16(W, A0, A1, h0, h1, h2, h3)                                    \
    A0 = __hfma2(H2(W[0]),  H2(h0.x), A0);                                \
    A1 = __hfma2(H2(W[1]),  H2(h0.y), A1);                                \
    A0 = __hfma2(H2(W[2]),  H2(h0.z), A0);                                \
    A1 = __hfma2(H2(W[3]),  H2(h0.w), A1);                                \
    A0 = __hfma2(H2(W[4]),  H2(h1.x), A0);                                \
    A1 = __hfma2(H2(W[5]),  H2(h1.y), A1);                                \
    A0 = __hfma2(H2(W[6]),  H2(h1.z), A0);                                \
    A1 = __hfma2(H2(W[7]),  H2(h1.w), A1);                                \
    A0 = __hfma2(H2(W[8]),  H2(h2.x), A0);                                \
    A1 = __hfma2(H2(W[9]),  H2(h2.y), A1);                                \
    A0 = __hfma2(H2(W[10]), H2(h2.z), A0);                                \
    A1 = __hfma2(H2(W[11]), H2(h2.w), A1);                                \
    A0 = __hfma2(H2(W[12]), H2(h3.x), A0);                                \
    A1 = __hfma2(H2(W[13]), H2(h3.y), A1);                                \
    A0 = __hfma2(H2(W[14]), H2(h3.z), A0);                                \
    A1 = __hfma2(H2(W[15]), H2(h3.w), A1);

// 16 tail pairs, weights from 4 LDS uint4 quads
#define G16T(T0, T1, T2, T3, A0, A1, h0, h1, h2, h3)                      \
    A0 = __hfma2(H2(T0.x), H2(h0.x), A0);                                 \
    A1 = __hfma2(H2(T0.y), H2(h0.y), A1);                                 \
    A0 = __hfma2(H2(T0.z), H2(h0.z), A0);                                 \
    A1 = __hfma2(H2(T0.w), H2(h0.w), A1);                                 \
    A0 = __hfma2(H2(T1.x), H2(h1.x), A0);                                 \
    A1 = __hfma2(H2(T1.y), H2(h1.y), A1);                                 \
    A0 = __hfma2(H2(T1.z), H2(h1.z), A0);                                 \
    A1 = __hfma2(H2(T1.w), H2(h1.w), A1);                                 \
    A0 = __hfma2(H2(T2.x), H2(h2.x), A0);                                 \
    A1 = __hfma2(H2(T2.y), H2(h2.y), A1);                                 \
    A0 = __hfma2(H2(T2.z), H2(h2.z), A0);                                 \
    A1 = __hfma2(H2(T2.w), H2(h2.w), A1);                                 \
    A0 = __hfma2(H2(T3.x), H2(h3.x), A0);                                 \
    A1 = __hfma2(H2(T3.y), H2(h3.y), A1);                                 \
    A0 = __hfma2(H2(T3.z), H2(h3.z), A0);                                 \
    A1 = __hfma2(H2(T3.w), H2(h3.w), A1);

__global__ void __launch_bounds__(512, 1)
__attribute__((amdgpu_waves_per_eu(2, 2)))
k_recur(const _Float16* __restrict__ Wht, const _Float16* __restrict__ gx,
        float* __restrict__ out)
{
    const int b    = blockIdx.x;
    const int tid  = threadIdx.x;      // 0..511
    const int j    = tid >> 1;         // hidden unit
    const int half = tid & 1;          // K-half owner
    const int ub   = half * 16;        // h uint4 base (pairs half*64 ..)

    __shared__ uint4 wl[16 * 512];                   // 128 KB tail weights
    __shared__ __align__(16) _Float16 hbuf[2][256];  // double-buffered h

    // ---- register-resident weights: pairs [half*64, half*64+48) per gate ----
    const u32x16* pA = (const u32x16*)(Wht + (size_t)(0 * 256 + j) * 256 + half * 128);
    const u32x16* pB = (const u32x16*)(Wht + (size_t)(1 * 256 + j) * 256 + half * 128);
    const u32x16* pC = (const u32x16*)(Wht + (size_t)(2 * 256 + j) * 256 + half * 128);
    const u32x16* pD = (const u32x16*)(Wht + (size_t)(3 * 256 + j) * 256 + half * 128);
    u32x16 wA0 = pA[0], wA1 = pA[1], wA2 = pA[2];
    u32x16 wB0 = pB[0], wB1 = pB[1], wB2 = pB[2];
    u32x16 wC0 = pC[0], wC1 = pC[1], wC2 = pC[2];
    u32x16 wD0 = pD[0], wD1 = pD[1], wD2 = pD[2];
    // ---- tail pairs [half*64+48, half*64+64) per gate -> LDS ----
#pragma unroll
    for (int g = 0; g < 4; ++g) {
        const uint4* src = (const uint4*)(Wht + (size_t)(g * 256 + j) * 256
                                          + half * 128 + 96);
#pragma unroll
        for (int i = 0; i < 4; ++i)
            wl[(g * 4 + i) * 512 + tid] = src[i];
    }

    if (tid < 256) hbuf[0][tid] = (_Float16)0.0f;
    float s = 0.0f;
    _Float16 gc0 = gx[(size_t)b * G4 + j];
    _Float16 gc1 = gx[(size_t)b * G4 + 256 + j];
    _Float16 gc2 = gx[(size_t)b * G4 + 512 + j];
    _Float16 gc3 = gx[(size_t)b * G4 + 768 + j];
    __syncthreads();

#pragma unroll 1
    for (int t = 0; t < T_STEPS; ++t) {
        _Float16 gn0 = (_Float16)0.0f, gn1 = (_Float16)0.0f;
        _Float16 gn2 = (_Float16)0.0f, gn3 = (_Float16)0.0f;
        if (t + 1 < T_STEPS) {
            const size_t m = ((size_t)(t + 1) * BATCH + b) * G4;
            gn0 = gx[m + j];       gn1 = gx[m + 256 + j];
            gn2 = gx[m + 512 + j]; gn3 = gx[m + 768 + j];
        }

        const uint4* hsrc = (const uint4*)hbuf[t & 1];
        __half2 aA0 = H2(0u), aA1 = H2(0u), aB0 = H2(0u), aB1 = H2(0u);
        __half2 aC0 = H2(0u), aC1 = H2(0u), aD0 = H2(0u), aD1 = H2(0u);

        {   // chunk position 0: pairs half*64 + [0,16)
            uint4 h0 = hsrc[ub + 0], h1 = hsrc[ub + 1];
            uint4 h2 = hsrc[ub + 2], h3 = hsrc[ub + 3];
            G16(wA0, aA0, aA1, h0, h1, h2, h3)
            G16(wB0, aB0, aB1, h0, h1, h2, h3)
            G16(wC0, aC0, aC1, h0, h1, h2, h3)
            G16(wD0, aD0, aD1, h0, h1, h2, h3)
        }
        {   // chunk position 1: pairs half*64 + [16,32)
            uint4 h0 = hsrc[ub + 4], h1 = hsrc[ub + 5];
            uint4 h2 = hsrc[ub + 6], h3 = hsrc[ub + 7];
            G16(wA1, aA0, aA1, h0, h1, h2, h3)
            G16(wB1, aB0, aB1, h0, h1, h2, h3)
            G16(wC1, aC0, aC1, h0, h1, h2, h3)
            G16(wD1, aD0, aD1, h0, h1, h2, h3)
        }
        {   // chunk position 2: pairs half*64 + [32,48)
            uint4 h0 = hsrc[ub + 8], h1 = hsrc[ub + 9];
            uint4 h2 = hsrc[ub + 10], h3 = hsrc[ub + 11];
            G16(wA2, aA0, aA1, h0, h1, h2, h3)
            G16(wB2, aB0, aB1, h0, h1, h2, h3)
            G16(wC2, aC0, aC1, h0, h1, h2, h3)
            G16(wD2, aD0, aD1, h0, h1, h2, h3)
        }
        {   // tail: pairs half*64 + [48,64), weights from LDS (per-gate quads)
            uint4 h0 = hsrc[ub + 12], h1 = hsrc[ub + 13];
            uint4 h2 = hsrc[ub + 14], h3 = hsrc[ub + 15];
            {
                uint4 t0 = wl[0 * 512 + tid], t1 = wl[1 * 512 + tid];
                uint4 t2 = wl[2 * 512 + tid], t3 = wl[3 * 512 + tid];
                G16T(t0, t1, t2, t3, aA0, aA1, h0, h1, h2, h3)
            }
            {
                uint4 t0 = wl[4 * 512 + tid], t1 = wl[5 * 512 + tid];
                uint4 t2 = wl[6 * 512 + tid], t3 = wl[7 * 512 + tid];
                G16T(t0, t1, t2, t3, aB0, aB1, h0, h1, h2, h3)
            }
            {
                uint4 t0 = wl[8 * 512 + tid], t1 = wl[9 * 512 + tid];
                uint4 t2 = wl[10 * 512 + tid], t3 = wl[11 * 512 + tid];
                G16T(t0, t1, t2, t3, aC0, aC1, h0, h1, h2, h3)
            }
            {
                uint4 t0 = wl[12 * 512 + tid], t1 = wl[13 * 512 + tid];
                uint4 t2 = wl[14 * 512 + tid], t3 = wl[15 * 512 + tid];
                G16T(t0, t1, t2, t3, aD0, aD1, h0, h1, h2, h3)
            }
        }

        // per-gate partial -> f32; combine halves via DPP shuffle; gc added
        // ONCE, after the combine (R8 bug: per-half add counted gc twice).
        __half2 rA = __hadd2(aA0, aA1), rB = __hadd2(aB0, aB1);
        __half2 rC = __hadd2(aC0, aC1), rD = __hadd2(aD0, aD1);
        float gA = __low2float(rA) + __high2float(rA);
        float gB = __low2float(rB) + __high2float(rB);
        float gC = __low2float(rC) + __high2float(rC);
        float gD = __low2float(rD) + __high2float(rD);
        gA += __shfl_xor(gA, 1, 64);
        gB += __shfl_xor(gB, 1, 64);
        gC += __shfl_xor(gC, 1, 64);
        gD += __shfl_xor(gD, 1, 64);
        gA += (float)gc0;
        gB += (float)gc1;
        gC += (float)gc2;
        gD += (float)gc3;

        float aa = fast_tanh(gA);
        float ii = fast_sigmoid(gB);
        float ff = fast_sigmoid(gC);
        float oo = fast_sigmoid(gD);
        s = aa * ii + s * ff;
        float h = fast_tanh(s) * oo;
        if (half == 0) {
            out[((size_t)t * BATCH + b) * HID + j] = h;
            hbuf[(t + 1) & 1][j] = (_Float16)h;
        }
        __syncthreads();

        gc0 = gn0; gc1 = gn1; gc2 = gn2; gc3 = gn3;
    }
}

extern "C" void kernel_launch(void* const* d_in, const int* in_sizes, int n_in,
                              void* d_out, int out_size, void* d_ws, size_t ws_size,
                              hipStream_t stream) {
    const float* X   = (const float*)d_in[0];
    const float* Wax = (const float*)d_in[1];
    const float* Wix = (const float*)d_in[2];
    const float* Wfx = (const float*)d_in[3];
    const float* Wox = (const float*)d_in[4];
    const float* Wah = (const float*)d_in[5];
    const float* Wih = (const float*)d_in[6];
    const float* Wfh = (const float*)d_in[7];
    const float* Woh = (const float*)d_in[8];
    const float* ba  = (const float*)d_in[9];
    const float* bi  = (const float*)d_in[10];
    const float* bf  = (const float*)d_in[11];
    const float* bo  = (const float*)d_in[12];

    _Float16* ws  = (_Float16*)d_ws;
    _Float16* Xh  = ws + XH_OFF;
    _Float16* Wxt = ws + WXT_OFF;
    _Float16* Wht = ws + WHT_OFF;
    _Float16* gxp = ws + GX_OFF;

    k_prep_x<<<dim3(GM * 256 / 4 / 256), dim3(256), 0, stream>>>(X, Xh);
    k_prep_w<<<dim3(2048), dim3(256), 0, stream>>>(Wax, Wix, Wfx, Wox,
                                                   Wah, Wih, Wfh, Woh, Wxt, Wht);
    k_gemm<<<dim3(GM / 128, G4 / 64), dim3(256), 0, stream>>>(
        Xh, Wxt, ba, bi, bf, bo, gxp);
    k_recur<<<dim3(BATCH), dim3(512), 0, stream>>>(Wht, gxp, (float*)d_out);
}